// Round 13
// baseline (2399.649 us; speedup 1.0000x reference)
//
#include <hip/hip_runtime.h>
#include <stdint.h>

typedef unsigned short u16;
typedef __bf16 bf16x8 __attribute__((ext_vector_type(8)));
typedef float f32x4 __attribute__((ext_vector_type(4)));

#define AS1 __attribute__((address_space(1)))
#define AS3 __attribute__((address_space(3)))

__device__ __forceinline__ void ld_lds16(const void* gp, void* lp) {
  __builtin_amdgcn_global_load_lds((AS1 void*)(void*)gp, (AS3 void*)lp, 16, 0, 0);
}

__device__ __forceinline__ u16 f2bf(float f) {
  uint32_t u = __float_as_uint(f);
  u += 0x7FFFu + ((u >> 16) & 1u);
  return (u16)(u >> 16);
}

__device__ __forceinline__ float fsig(float x) { return 1.0f / (1.0f + __expf(-x)); }
__device__ __forceinline__ float ftanhf(float x) {
  float e = __expf(-2.0f * fabsf(x));
  float t = (1.0f - e) / (1.0f + e);
  return copysignf(t, x);
}

#define LSEQ 100
#define EMB 512
#define HID 1024
#define KDIM 1536

// ---------------- LSTM step ----------------
// 512 thr, 8 waves = 2m x 2n x 2k (wave 64x64 over a 32-k half; R12 geometry, verified).
// B (weights) in FRAGMENT-MAJOR Wfm, loaded straight to named register sets B0/B1
// (double-buffered, even/odd peeled loop -> all reg indices compile-time). No LDS for B.
// A staged via global_load_lds into 4 x 16 KB buffers (64 KB total), zero-conflict swizzle.
// Counted vmcnt: steady vmcnt(2) covers {A(kt+2) in flight}; B has 1-iter lookahead.
__global__ __launch_bounds__(512, 2) void k_step(
    const u16* __restrict__ emb, const u16* __restrict__ Wfm,
    const float* __restrict__ b2, const float* __restrict__ p_i,
    const float* __restrict__ p_f, const float* __restrict__ p_o,
    const int* __restrict__ tokQ, const int* __restrict__ tokR,
    const int* __restrict__ lenQ, const int* __restrict__ lenR,
    const u16* __restrict__ h_cur, u16* __restrict__ h_nxt,
    float* __restrict__ c_st, int t)
{
  __shared__ __align__(16) u16 sb[4 * 8192];  // 4 A-bufs x 16 KB = 64 KB
  const int tid = threadIdx.x;
  const int lane = tid & 63, wid = tid >> 6;        // 8 waves
  const int kw = wid >> 2;                          // k-half 0/1
  const int wm = (wid >> 1) & 1, wn = wid & 1;      // 2m x 2n; wave tile 64 x 64
  const int lane_lo = lane & 15, lane_hi = lane >> 4;
  const int g = blockIdx.x;
  const int bx = (g & 7) * 4 + ((g >> 3) & 3);      // XCD swizzle
  const int by = g >> 5;

  f32x4 acc[4][4];
  const f32x4 zz = {0.f, 0.f, 0.f, 0.f};
#pragma unroll
  for (int a = 0; a < 4; ++a)
#pragma unroll
    for (int bb = 0; bb < 4; ++bb) acc[a][bb] = zz;

  // ---- token loads FIRST (longest dependency chain) ----
  int tokv[2], rowe[2], rowi[2], ldsoA[2], srcoA[2];
#pragma unroll
  for (int j = 0; j < 2; ++j) {
    const int ch = j * 512 + tid;        // 1024 A chunks; 8 chunks (128 B) per row
    const int r = ch >> 3;
    const int srcoff = ((ch & 7) ^ (r & 7)) * 8;   // zero-conflict XOR swizzle (u16 elems)
    const int m = by * 128 + r, e = m >> 9, i = m & 511;
    tokv[j] = (e ? tokR : tokQ)[i * LSEQ + t];
    rowe[j] = e; rowi[j] = i;
    srcoA[j] = srcoff;
    ldsoA[j] = ch * 8;
  }

  // ---- epilogue operand prefetch (oldest in vmcnt; hidden under K-loop) ----
  const int colbase = bx * 128 + wn * 64;
  const int h = ((colbase >> 6) << 4) + lane_lo;
  const int mo = kw * 2;                 // owned mi base (address math only)
  float b2v[4];
#pragma unroll
  for (int gg = 0; gg < 4; ++gg) b2v[gg] = b2[colbase + gg * 16 + lane_lo];
  const float pi = p_i[h], pf = p_f[h], po = p_o[h];
  int lenv[2][4];
  float cold[2][4];
  u16 hprev[2][4];
#pragma unroll
  for (int m2 = 0; m2 < 2; ++m2)
#pragma unroll
    for (int r = 0; r < 4; ++r) {
      const int m = by * 128 + wm * 64 + (mo + m2) * 16 + lane_hi * 4 + r;
      const int e = m >> 9, i = m & 511;
      lenv[m2][r] = e ? lenR[i] : lenQ[i];
      const size_t ci = (size_t)(e * 512 + i) * HID + h;
      cold[m2][r] = c_st[ci];
      hprev[m2][r] = h_cur[ci];
    }
  __builtin_amdgcn_sched_barrier(0);  // pin: prologue vmem before staged loads

  // ---- staging pointers ----
  const u16* pAx[2];
  const u16* pAh[2];
#pragma unroll
  for (int j = 0; j < 2; ++j) {
    pAx[j] = emb + (size_t)tokv[j] * EMB + srcoA[j];
    pAh[j] = h_cur + (size_t)(rowe[j] * 512 + rowi[j]) * HID - 512 + srcoA[j];  // kb>=512 when used
  }
  // fragment-major W base for this wave's (bx, wn, kw)
  const u16* pWl = Wfm + (size_t)(((bx * 2 + wn) * 2) + kw) * 49152 + lane * 8;

  auto stageA = [&](int kt) {
    const int kb = kt * 64;
    u16* lA = sb + (kt & 3) * 8192;
    const bool isx = kb < EMB;  // uniform per kt
#pragma unroll
    for (int j = 0; j < 2; ++j) ld_lds16((isx ? pAx[j] : pAh[j]) + kb, lA + ldsoA[j]);
  };

  auto loadB = [&](int kt, bf16x8 (&Bs)[4]) {
    const u16* p = pWl + kt * 2048;
#pragma unroll
    for (int ni = 0; ni < 4; ++ni)
      Bs[ni] = *(const bf16x8*)(p + ni * 512);
  };

  auto compute = [&](int kt, const bf16x8 (&Bs)[4]) {
    const char* lA = (const char*)(sb + (kt & 3) * 8192);
    bf16x8 aF[4];
#pragma unroll
    for (int mi = 0; mi < 4; ++mi) {
      const int rr = wm * 64 + mi * 16 + lane_lo;
      const int byo = rr * 128 + ((kw * 64 + lane_hi * 16) ^ ((rr & 7) << 4));
      aF[mi] = *(const bf16x8*)(lA + byo);
    }
#pragma unroll
    for (int mi = 0; mi < 4; ++mi)
#pragma unroll
      for (int ni = 0; ni < 4; ++ni)
        acc[mi][ni] = __builtin_amdgcn_mfma_f32_16x16x32_bf16(aF[mi], Bs[ni], acc[mi][ni], 0, 0, 0);
  };

  bf16x8 B0[4], B1[4];

  // ---- prologue: B(0) then A(0..2) (order matters for vmcnt counting) ----
  loadB(0, B0);
  stageA(0); stageA(1); stageA(2);

  // Per iter kt: [wait][barrier][loadB(kt+1)][stageA(kt+3)][MFMA(kt)]
  // Steady-state outstanding at wait: A(kt+1)x2, B(kt)x4, A(kt+2)x2 -> vmcnt(2)
  // keeps A(kt+2) in flight, guarantees B(kt)+A(kt) landed.
#define STEP_ITER(KT, BU, BF, VM)                                   \
  asm volatile("s_waitcnt vmcnt(" #VM ")" ::: "memory");            \
  __builtin_amdgcn_s_barrier();                                     \
  __builtin_amdgcn_sched_barrier(0);                                \
  if ((KT) < 23) loadB((KT) + 1, BF);                               \
  if ((KT) < 21) stageA((KT) + 3);                                  \
  __builtin_amdgcn_s_setprio(1);                                    \
  compute((KT), BU);                                                \
  __builtin_amdgcn_s_setprio(0);

  STEP_ITER(0, B0, B1, 4)
  STEP_ITER(1, B1, B0, 2)
  for (int j = 1; j <= 10; ++j) {
    const int kt = 2 * j;
    STEP_ITER(kt, B0, B1, 2)
    STEP_ITER(kt + 1, B1, B0, 2)
  }
  STEP_ITER(22, B0, B1, 0)
  STEP_ITER(23, B1, B0, 0)
#undef STEP_ITER

  // ---- k-pair combine through LDS (aliases A bufs -> barrier BOTH sides) ----
  __syncthreads();   // all waves done reading buf 3 before overwrite
  float* cmbf = (float*)sb;
  const int pair = wm * 2 + wn;
  {
    float* wslot = cmbf + (pair * 2 + kw) * 2048;   // 8 slots x 8 KB = 64 KB
    if (kw == 0) {
#pragma unroll
      for (int m2 = 0; m2 < 2; ++m2)
#pragma unroll
        for (int ni = 0; ni < 4; ++ni)
          *(f32x4*)(wslot + (m2 * 4 + ni) * 256 + lane * 4) = acc[2 + m2][ni];
    } else {
#pragma unroll
      for (int m2 = 0; m2 < 2; ++m2)
#pragma unroll
        for (int ni = 0; ni < 4; ++ni)
          *(f32x4*)(wslot + (m2 * 4 + ni) * 256 + lane * 4) = acc[m2][ni];
    }
  }
  __syncthreads();
  f32x4 accF[2][4];
  {
    const float* rslot = cmbf + (pair * 2 + (kw ^ 1)) * 2048;
    if (kw == 0) {
#pragma unroll
      for (int m2 = 0; m2 < 2; ++m2)
#pragma unroll
        for (int ni = 0; ni < 4; ++ni)
          accF[m2][ni] = acc[m2][ni] + *(const f32x4*)(rslot + (m2 * 4 + ni) * 256 + lane * 4);
    } else {
#pragma unroll
      for (int m2 = 0; m2 < 2; ++m2)
#pragma unroll
        for (int ni = 0; ni < 4; ++ni)
          accF[m2][ni] = acc[2 + m2][ni] + *(const f32x4*)(rslot + (m2 * 4 + ni) * 256 + lane * 4);
    }
  }

  // ----- fused gate epilogue (R12 verbatim): lane owns one h, 8 rows; ni == gate -----
#pragma unroll
  for (int m2 = 0; m2 < 2; ++m2) {
#pragma unroll
    for (int r = 0; r < 4; ++r) {
      const int m = by * 128 + wm * 64 + (mo + m2) * 16 + lane_hi * 4 + r;
      const int e = m >> 9, i = m & 511;
      const size_t ci = (size_t)(e * 512 + i) * HID + h;
      u16 hv;
      if (t < lenv[m2][r]) {
        const float c_old = cold[m2][r];
        const float zi = accF[m2][0][r] + b2v[0] + pi * c_old;
        const float zj = accF[m2][1][r] + b2v[1];
        const float zf = accF[m2][2][r] + b2v[2] + pf * c_old;  // FORGET_BIAS folded in b2
        const float zo = accF[m2][3][r] + b2v[3];
        const float ig = fsig(zi), fg = fsig(zf);
        const float cn = fg * c_old + ig * ftanhf(zj);
        const float og = fsig(zo + po * cn);
        const float hn = og * ftanhf(cn);
        c_st[ci] = cn;
        hv = f2bf(hn);
      } else {
        hv = hprev[m2][r];
      }
      h_nxt[ci] = hv;
    }
  }
}

// ---------------- generic bf16 GEMM: C[m][n] = sum_k A[m][k] * Bn[n][k] ----------------
template <int OUT_BF16>
__global__ __launch_bounds__(256) void k_gemm(
    const u16* __restrict__ A, const u16* __restrict__ Bn,
    void* __restrict__ Cout, int K, int ldc)
{
  __shared__ u16 lA[128 * 64];
  __shared__ u16 lB[128 * 64];
  const int tid = threadIdx.x;
  const int lane = tid & 63, wid = tid >> 6;
  const int wm = wid >> 1, wn = wid & 1;
  const int lane_lo = lane & 15, lane_hi = lane >> 4;
  const int bx = blockIdx.x, by = blockIdx.y;

  f32x4 acc[4][4];
  const f32x4 zz = {0.f, 0.f, 0.f, 0.f};
#pragma unroll
  for (int a = 0; a < 4; ++a)
#pragma unroll
    for (int bb = 0; bb < 4; ++bb) acc[a][bb] = zz;

  const int nkt = K >> 6;
  for (int kt = 0; kt < nkt; ++kt) {
    const int kb = kt * 64;
#pragma unroll
    for (int j = 0; j < 4; ++j) {
      const int cbase = (j * 4 + wid) * 64;
      const int ch = cbase + lane;
      const int r = ch >> 3;
      const int srcoff = ((((ch & 7) << 4) ^ ((r & 7) << 4)) >> 1);
      ld_lds16(A + (size_t)(by * 128 + r) * K + kb + srcoff, &lA[cbase * 8]);
    }
#pragma unroll
    for (int j = 0; j < 4; ++j) {
      const int cbase = (j * 4 + wid) * 64;
      const int ch = cbase + lane;
      const int r = ch >> 3;
      const int srcoff = ((((ch & 7) << 4) ^ ((r & 7) << 4)) >> 1);
      ld_lds16(Bn + (size_t)(bx * 128 + r) * K + kb + srcoff, &lB[cbase * 8]);
    }
    __syncthreads();
#pragma unroll
    for (int kk = 0; kk < 2; ++kk) {
      bf16x8 aF[4], bF[4];
#pragma unroll
      for (int mi = 0; mi < 4; ++mi) {
        const int rr = wm * 64 + mi * 16 + lane_lo;
        const int byo = rr * 128 + ((kk * 64 + lane_hi * 16) ^ ((rr & 7) << 4));
        aF[mi] = *(const bf16x8*)((const char*)lA + byo);
      }
#pragma unroll
      for (int ni = 0; ni < 4; ++ni) {
        const int rr = wn * 64 + ni * 16 + lane_lo;
        const int byo = rr * 128 + ((kk * 64 + lane_hi * 16) ^ ((rr & 7) << 4));
        bF[ni] = *(const bf16x8*)((const char*)lB + byo);
      }
#pragma unroll
      for (int mi = 0; mi < 4; ++mi)
#pragma unroll
        for (int ni = 0; ni < 4; ++ni)
          acc[mi][ni] = __builtin_amdgcn_mfma_f32_16x16x32_bf16(aF[mi], bF[ni], acc[mi][ni], 0, 0, 0);
    }
    __syncthreads();
  }

#pragma unroll
  for (int mi = 0; mi < 4; ++mi)
#pragma unroll
    for (int r = 0; r < 4; ++r) {
      const int m = by * 128 + wm * 64 + mi * 16 + lane_hi * 4 + r;
#pragma unroll
      for (int ni = 0; ni < 4; ++ni) {
        const int col = bx * 128 + wn * 64 + ni * 16 + lane_lo;
        const float v = acc[mi][ni][r];
        if (OUT_BF16) ((u16*)Cout)[(size_t)m * ldc + col] = f2bf(v);
        else ((float*)Cout)[(size_t)m * ldc + col] = v;
      }
    }
}

// ---------------- prep kernels ----------------
// Fragment-major W pack for k_step:
// Wfm[((((bx*2+wn)*2+kw)*24+kt)*4+ni)*512 + lane*8 + e] = bf16(W[k][n])
//   n' = ((h>>4)<<6)+(g<<4)+(h&15) (gate perm; n = g*1024+h), bx=n'>>7, wn=(n'>>6)&1,
//   ni=(n'>>4)&3, lane_lo=n'&15; k = kt*64 + kw*32 + lane_hi*8 + e, lane=lane_hi*16+lane_lo.
__global__ void k_pack(const float* __restrict__ W, u16* __restrict__ Wfm) {
  __shared__ float tile[64][65];
  const int n0 = blockIdx.x * 64;   // orig col base (64-aligned, no gate straddle)
  const int k0 = blockIdx.y * 64;
  const int tid = threadIdx.x;
  const int c = tid & 63, rq = tid >> 6;
  for (int rr = 0; rr < 64; rr += 4)
    tile[rr + rq][c] = W[(size_t)(k0 + rr + rq) * 4096 + n0 + c];
  __syncthreads();
  const int gate = n0 >> 10;
  const int h0 = n0 & 1023;
  const int kt = k0 >> 6;
  for (int cc = tid; cc < 512; cc += 256) {
    const int hh = cc >> 3;          // col within tile
    const int k8 = cc & 7;           // 8-elem k-group within tile
    const int h = h0 + hh;
    const int np = ((h >> 4) << 6) + (gate << 4) + (h & 15);
    const int bx = np >> 7, wn = (np >> 6) & 1, ni = (np >> 4) & 3, llo = np & 15;
    const int kw = k8 >> 2, lhi = k8 & 3;
    const int lane = lhi * 16 + llo;
    u16 oc[8];
#pragma unroll
    for (int e = 0; e < 8; ++e)
      oc[e] = f2bf(tile[k8 * 8 + e][hh]);
    const size_t o = ((((size_t)(bx * 2 + wn) * 2 + kw) * 24 + kt) * 4 + ni) * 512 + lane * 8;
    *(ushort4*)(Wfm + o)     = *(ushort4*)&oc[0];
    *(ushort4*)(Wfm + o + 4) = *(ushort4*)&oc[4];
  }
}

// out[n'][k] (bf16) = in[k][n] (f32); perm!=0 applies gate-interleave permutation (N_=4096)
__global__ void k_transpose(const float* __restrict__ in, u16* __restrict__ out,
                            int K_, int N_, int perm)
{
  __shared__ float tile[64][65];
  const int tid = threadIdx.x;
  const int k0 = blockIdx.y * 64, n0 = blockIdx.x * 64;
  const int c = tid & 63, rq = tid >> 6;
  for (int rr = 0; rr < 64; rr += 4)
    tile[rr + rq][c] = in[(size_t)(k0 + rr + rq) * N_ + n0 + c];
  __syncthreads();
  for (int nr0 = 0; nr0 < 64; nr0 += 4) {
    const int nr = nr0 + rq;
    const int n = n0 + nr;
    int np = n;
    if (perm) {
      const int g = n >> 10, hh = n & 1023;
      np = ((hh >> 4) << 6) + (g << 4) + (hh & 15);
    }
    out[(size_t)np * K_ + k0 + c] = f2bf(tile[c][nr]);
  }
}

__global__ void k_bias(const float* __restrict__ b, float* __restrict__ b2) {
  const int n = blockIdx.x * 256 + threadIdx.x;
  if (n < 4096) {
    const int g = n >> 10, hh = n & 1023;
    const int np = ((hh >> 4) << 6) + (g << 4) + (hh & 15);
    b2[np] = b[n] + (g == 2 ? 2.0f : 0.0f);
  }
}

__global__ void k_cvt(const float4* __restrict__ in, u16* __restrict__ out, size_t n4) {
  size_t idx = (size_t)blockIdx.x * blockDim.x + threadIdx.x;
  const size_t stride = (size_t)gridDim.x * blockDim.x;
  for (; idx < n4; idx += stride) {
    const float4 v = in[idx];
    ushort4 o;
    o.x = f2bf(v.x); o.y = f2bf(v.y); o.z = f2bf(v.z); o.w = f2bf(v.w);
    *(ushort4*)(out + idx * 4) = o;
  }
}

__global__ void k_zero(uint4* __restrict__ p, size_t n) {
  size_t idx = (size_t)blockIdx.x * blockDim.x + threadIdx.x;
  const size_t stride = (size_t)gridDim.x * blockDim.x;
  const uint4 z = {0u, 0u, 0u, 0u};
  for (; idx < n; idx += stride) p[idx] = z;
}

// ---------------- loss ----------------
__global__ void k_loss1(const float* __restrict__ D, float* __restrict__ part) {
  __shared__ float sd[256];
  const int tid = threadIdx.x;
  float s = 0.f;
  for (int idx = blockIdx.x * 256 + tid; idx < 512 * 512; idx += 256 * 256) {
    const float x = D[idx];
    float sp;
    if (x > 20.f) sp = x;
    else if (x < -20.f) sp = __expf(x);
    else sp = __logf(1.0f + __expf(x));
    if ((idx >> 9) == (idx & 511)) sp -= x;
    s += sp;
  }
  sd[tid] = s;
  __syncthreads();
  for (int o = 128; o > 0; o >>= 1) { if (tid < o) sd[tid] += sd[tid + o]; __syncthreads(); }
  if (tid == 0) part[blockIdx.x] = sd[0];
}

__global__ void k_loss2(const float* __restrict__ part, float* __restrict__ out) {
  __shared__ float sd[256];
  const int tid = threadIdx.x;
  sd[tid] = part[tid];
  __syncthreads();
  for (int o = 128; o > 0; o >>= 1) { if (tid < o) sd[tid] += sd[tid + o]; __syncthreads(); }
  if (tid == 0) out[0] = sd[0] * (1.0f / (512.0f * 512.0f));
}

// ---------------- launch ----------------
extern "C" void kernel_launch(void* const* d_in, const int* in_sizes, int n_in,
                              void* d_out, int out_size, void* d_ws, size_t ws_size,
                              hipStream_t stream)
{
  const float* embF = (const float*)d_in[0];
  const float* W    = (const float*)d_in[1];
  const float* b    = (const float*)d_in[2];
  const float* p_i  = (const float*)d_in[3];
  const float* p_f  = (const float*)d_in[4];
  const float* p_o  = (const float*)d_in[5];
  const float* Mm   = (const float*)d_in[6];
  const int* tokQ   = (const int*)d_in[7];
  const int* tokR   = (const int*)d_in[8];
  const int* lenQ   = (const int*)d_in[9];
  const int* lenR   = (const int*)d_in[10];
  float* out = (float*)d_out;

  char* ws = (char*)d_ws;
  const size_t OFF_EMB  = 0;                       // 50000*512*2 = 51,200,000
  const size_t OFF_WFM  = 51200000;                // 4096*1536*2 = 12,582,912 (fragment-major)
  const size_t OFF_MT   = OFF_WFM + 12582912;      // 1024*1024*2 =  2,097,152
  const size_t OFF_B2   = OFF_MT + 2097152;        // 4096*4
  const size_t OFF_H    = OFF_B2 + 16384;          // 2buf*2enc*512*1024*2 = 4,194,304
  const size_t OFF_C    = OFF_H + 4194304;         // 2enc*512*1024*4 = 4,194,304
  const size_t OFF_QT   = OFF_C + 4194304;         // 512*1024*2 = 1,048,576
  const size_t OFF_PART = OFF_QT + 1048576;        // 256*4
  const size_t NEED = OFF_PART + 1024;
  if (ws_size < NEED) return;

  u16* embB  = (u16*)(ws + OFF_EMB);
  u16* Wfm   = (u16*)(ws + OFF_WFM);
  u16* MT    = (u16*)(ws + OFF_MT);
  float* b2  = (float*)(ws + OFF_B2);
  u16* hbuf  = (u16*)(ws + OFF_H);
  float* cst = (float*)(ws + OFF_C);
  u16* qt    = (u16*)(ws + OFF_QT);
  float* part= (float*)(ws + OFF_PART);

  // prep
  k_cvt<<<dim3(2048), dim3(256), 0, stream>>>((const float4*)embF, embB, (size_t)(50000 * 512 / 4));
  k_pack<<<dim3(64, 24), dim3(256), 0, stream>>>(W, Wfm);
  k_transpose<<<dim3(16, 16), dim3(256), 0, stream>>>(Mm, MT, 1024, 1024, 0);
  k_bias<<<dim3(16), dim3(256), 0, stream>>>(b, b2);
  k_zero<<<dim3(256), dim3(256), 0, stream>>>((uint4*)hbuf, 131072);   // h buf0 (2 MB)
  k_zero<<<dim3(256), dim3(256), 0, stream>>>((uint4*)cst, 262144);    // c (4 MB)

  // recurrence: h double-buffered; t reads buf (t&1), writes buf ((t+1)&1); final state in buf 0
  const size_t HBUFSTRIDE = (size_t)2 * 512 * 1024;  // u16 elems per buffer
  for (int t = 0; t < 100; ++t) {
    u16* hc = hbuf + (size_t)(t & 1) * HBUFSTRIDE;
    u16* hn = hbuf + (size_t)((t + 1) & 1) * HBUFSTRIDE;
    k_step<<<dim3(256), dim3(512), 0, stream>>>(embB, Wfm, b2, p_i, p_f, p_o,
                                                tokQ, tokR, lenQ, lenR, hc, hn, cst, t);
  }

  // q_t = h_q @ M  (A = enc0 of buf0; B = M^T rows)
  k_gemm<1><<<dim3(8, 4), dim3(256), 0, stream>>>(hbuf, MT, qt, 1024, 1024);
  // distances = q_t @ h_r^T  (B rows = enc1 final h)
  k_gemm<0><<<dim3(4, 4), dim3(256), 0, stream>>>(qt, hbuf + (size_t)512 * 1024, out, 1024, 512);

  k_loss1<<<dim3(256), dim3(256), 0, stream>>>(out, part);
  k_loss2<<<dim3(1), dim3(256), 0, stream>>>(part, out + 262144);
}

// Round 14
// 2114.181 us; speedup vs baseline: 1.1350x; 1.1350x over previous
//
#include <hip/hip_runtime.h>
#include <stdint.h>

typedef unsigned short u16;
typedef __bf16 bf16x8 __attribute__((ext_vector_type(8)));
typedef float f32x4 __attribute__((ext_vector_type(4)));

#define AS1 __attribute__((address_space(1)))
#define AS3 __attribute__((address_space(3)))

__device__ __forceinline__ void ld_lds16(const void* gp, void* lp) {
  __builtin_amdgcn_global_load_lds((AS1 void*)(void*)gp, (AS3 void*)lp, 16, 0, 0);
}

__device__ __forceinline__ u16 f2bf(float f) {
  uint32_t u = __float_as_uint(f);
  u += 0x7FFFu + ((u >> 16) & 1u);
  return (u16)(u >> 16);
}

__device__ __forceinline__ float fsig(float x) { return 1.0f / (1.0f + __expf(-x)); }
__device__ __forceinline__ float ftanhf(float x) {
  float e = __expf(-2.0f * fabsf(x));
  float t = (1.0f - e) / (1.0f + e);
  return copysignf(t, x);
}

#define LSEQ 100
#define EMB 512
#define HID 1024
#define KDIM 1536

// ---------------- LSTM step ----------------
// 512 thr, 8 waves = 2m x 2n x 2k (R12 geometry, verified). B from fragment-major Wfm
// straight to named register sets S0/S1 (1-pair lookahead ~2400cyc; no LDS for B).
// A-only LDS tiles (16 KB) x 6 buffers = 96 KB -> TWO K-tiles per barrier:
// 12 waits + 12 barriers (vs 24), uniform counted vmcnt(4). A has 2-pair lookahead
// (h rows are HBM-cold after the kernel boundary). k-halves combine via LDS, static idx.
__global__ __launch_bounds__(512, 2) void k_step(
    const u16* __restrict__ emb, const u16* __restrict__ Wfm,
    const float* __restrict__ b2, const float* __restrict__ p_i,
    const float* __restrict__ p_f, const float* __restrict__ p_o,
    const int* __restrict__ tokQ, const int* __restrict__ tokR,
    const int* __restrict__ lenQ, const int* __restrict__ lenR,
    const u16* __restrict__ h_cur, u16* __restrict__ h_nxt,
    float* __restrict__ c_st, int t)
{
  __shared__ __align__(16) u16 sb[6 * 8192];  // 6 A-bufs x 16 KB = 96 KB
  const int tid = threadIdx.x;
  const int lane = tid & 63, wid = tid >> 6;        // 8 waves
  const int kw = wid >> 2;                          // k-half 0/1
  const int wm = (wid >> 1) & 1, wn = wid & 1;      // 2m x 2n; wave tile 64 x 64
  const int lane_lo = lane & 15, lane_hi = lane >> 4;
  const int g = blockIdx.x;
  const int bx = (g & 7) * 4 + ((g >> 3) & 3);      // XCD swizzle
  const int by = g >> 5;

  f32x4 acc[4][4];
  const f32x4 zz = {0.f, 0.f, 0.f, 0.f};
#pragma unroll
  for (int a = 0; a < 4; ++a)
#pragma unroll
    for (int bb = 0; bb < 4; ++bb) acc[a][bb] = zz;

  // ---- token loads FIRST (longest dependency chain) ----
  int tokv[2], rowe[2], rowi[2], ldsoA[2], srcoA[2];
#pragma unroll
  for (int j = 0; j < 2; ++j) {
    const int ch = j * 512 + tid;        // 1024 A chunks; 8 chunks (128 B) per row
    const int r = ch >> 3;
    const int srcoff = ((ch & 7) ^ (r & 7)) * 8;   // zero-conflict XOR swizzle (u16 elems)
    const int m = by * 128 + r, e = m >> 9, i = m & 511;
    tokv[j] = (e ? tokR : tokQ)[i * LSEQ + t];
    rowe[j] = e; rowi[j] = i;
    srcoA[j] = srcoff;
    ldsoA[j] = ch * 8;
  }

  // ---- epilogue operand prefetch (oldest in vmcnt; hidden under K-loop) ----
  const int colbase = bx * 128 + wn * 64;
  const int h = ((colbase >> 6) << 4) + lane_lo;
  const int mo = kw * 2;                 // owned mi base (address math only)
  float b2v[4];
#pragma unroll
  for (int gg = 0; gg < 4; ++gg) b2v[gg] = b2[colbase + gg * 16 + lane_lo];
  const float pi = p_i[h], pf = p_f[h], po = p_o[h];
  int lenv[2][4];
  float cold[2][4];
  u16 hprev[2][4];
#pragma unroll
  for (int m2 = 0; m2 < 2; ++m2)
#pragma unroll
    for (int r = 0; r < 4; ++r) {
      const int m = by * 128 + wm * 64 + (mo + m2) * 16 + lane_hi * 4 + r;
      const int e = m >> 9, i = m & 511;
      lenv[m2][r] = e ? lenR[i] : lenQ[i];
      const size_t ci = (size_t)(e * 512 + i) * HID + h;
      cold[m2][r] = c_st[ci];
      hprev[m2][r] = h_cur[ci];
    }
  __builtin_amdgcn_sched_barrier(0);  // pin: prologue vmem before staged loads

  // ---- staging pointers ----
  const u16* pAx[2];
  const u16* pAh[2];
#pragma unroll
  for (int j = 0; j < 2; ++j) {
    pAx[j] = emb + (size_t)tokv[j] * EMB + srcoA[j];
    pAh[j] = h_cur + (size_t)(rowe[j] * 512 + rowi[j]) * HID - 512 + srcoA[j];  // +T*64 (>=512) when used
  }
  // fragment-major W base for this wave's (bx, wn, kw) — layout identical to R13 k_pack (verified)
  const u16* pWl = Wfm + (size_t)(((bx * 2 + wn) * 2) + kw) * 49152 + lane * 8;

  bf16x8 S0[8], S1[8];   // two named B sets: frags [tile0: 0..3][tile1: 4..7]

#define LOADB(P, S) do {                                                     \
    _Pragma("unroll")                                                        \
    for (int ni = 0; ni < 4; ++ni) {                                         \
      S[ni]     = *(const bf16x8*)(pWl + (2*(P))     * 2048 + ni * 512);     \
      S[4 + ni] = *(const bf16x8*)(pWl + (2*(P) + 1) * 2048 + ni * 512);     \
    } } while (0)

#define STAGE_T(T) do {                                                      \
    u16* lA_ = sb + ((T) % 6) * 8192;                                        \
    if ((T) < 8) {                                                           \
      ld_lds16(pAx[0] + (T) * 64, lA_ + ldsoA[0]);                           \
      ld_lds16(pAx[1] + (T) * 64, lA_ + ldsoA[1]);                           \
    } else {                                                                 \
      ld_lds16(pAh[0] + (T) * 64, lA_ + ldsoA[0]);                           \
      ld_lds16(pAh[1] + (T) * 64, lA_ + ldsoA[1]);                           \
    } } while (0)

#define CTILE(T, S, OFS) do {                                                \
    const char* lAp_ = (const char*)(sb + ((T) % 6) * 8192);                 \
    bf16x8 aF_[4];                                                           \
    _Pragma("unroll")                                                        \
    for (int mi = 0; mi < 4; ++mi) {                                         \
      const int rr_ = wm * 64 + mi * 16 + lane_lo;                           \
      const int byo_ = rr_ * 128 + ((kw * 64 + lane_hi * 16) ^ ((rr_ & 7) << 4)); \
      aF_[mi] = *(const bf16x8*)(lAp_ + byo_);                               \
    }                                                                        \
    _Pragma("unroll")                                                        \
    for (int mi = 0; mi < 4; ++mi)                                           \
      _Pragma("unroll")                                                      \
      for (int ni = 0; ni < 4; ++ni)                                         \
        acc[mi][ni] = __builtin_amdgcn_mfma_f32_16x16x32_bf16(aF_[mi], S[(OFS) + ni], acc[mi][ni], 0, 0, 0); \
    } while (0)

  // ---- prologue: B(pair0); A tiles 0..3 (pairs 0,1). Queue: B0(8), A(8). ----
  LOADB(0, S0);
  STAGE_T(0); STAGE_T(1); STAGE_T(2); STAGE_T(3);

  // Per pair J: [wait vmcnt][barrier][loadB(J+1)][stageA pair J+2][MFMA tiles 2J,2J+1]
  // Steady queue at wait: A(J)4, B(J)8, A(J+1)4 -> vmcnt(4) forces A(J),B(J).
#define PAIR(J, SU, SL, VM)                                                  \
  asm volatile("s_waitcnt vmcnt(" #VM ")" ::: "memory");                     \
  __builtin_amdgcn_s_barrier();                                              \
  __builtin_amdgcn_sched_barrier(0);                                         \
  if ((J) <= 10) { LOADB((J) + 1, SL); }                                     \
  if ((J) <= 9)  { STAGE_T(2 * (J) + 4); STAGE_T(2 * (J) + 5); }             \
  __builtin_amdgcn_s_setprio(1);                                             \
  CTILE(2 * (J),     SU, 0);                                                 \
  CTILE(2 * (J) + 1, SU, 4);                                                 \
  __builtin_amdgcn_s_setprio(0);

  PAIR(0,  S0, S1, 4)
  PAIR(1,  S1, S0, 4)
  PAIR(2,  S0, S1, 4)
  PAIR(3,  S1, S0, 4)
  PAIR(4,  S0, S1, 4)
  PAIR(5,  S1, S0, 4)
  PAIR(6,  S0, S1, 4)
  PAIR(7,  S1, S0, 4)
  PAIR(8,  S0, S1, 4)
  PAIR(9,  S1, S0, 4)
  PAIR(10, S0, S1, 4)
  PAIR(11, S1, S0, 0)
#undef PAIR
#undef CTILE
#undef STAGE_T
#undef LOADB

  // ---- k-pair combine via LDS slots in bufs 0-3 (tiles 22,23 live in bufs 4,5: disjoint) ----
  float* cmbf = (float*)sb;
  const int pair = wm * 2 + wn;
  {
    float* wslot = cmbf + (pair * 2 + kw) * 2048;   // 8 slots x 8 KB = 64 KB
    if (kw == 0) {
#pragma unroll
      for (int m2 = 0; m2 < 2; ++m2)
#pragma unroll
        for (int ni = 0; ni < 4; ++ni)
          *(f32x4*)(wslot + (m2 * 4 + ni) * 256 + lane * 4) = acc[2 + m2][ni];
    } else {
#pragma unroll
      for (int m2 = 0; m2 < 2; ++m2)
#pragma unroll
        for (int ni = 0; ni < 4; ++ni)
          *(f32x4*)(wslot + (m2 * 4 + ni) * 256 + lane * 4) = acc[m2][ni];
    }
  }
  __syncthreads();
  f32x4 accF[2][4];
  {
    const float* rslot = cmbf + (pair * 2 + (kw ^ 1)) * 2048;
    if (kw == 0) {
#pragma unroll
      for (int m2 = 0; m2 < 2; ++m2)
#pragma unroll
        for (int ni = 0; ni < 4; ++ni)
          accF[m2][ni] = acc[m2][ni] + *(const f32x4*)(rslot + (m2 * 4 + ni) * 256 + lane * 4);
    } else {
#pragma unroll
      for (int m2 = 0; m2 < 2; ++m2)
#pragma unroll
        for (int ni = 0; ni < 4; ++ni)
          accF[m2][ni] = acc[2 + m2][ni] + *(const f32x4*)(rslot + (m2 * 4 + ni) * 256 + lane * 4);
    }
  }

  // ----- fused gate epilogue (R12 verbatim): lane owns one h, 8 rows; ni == gate -----
#pragma unroll
  for (int m2 = 0; m2 < 2; ++m2) {
#pragma unroll
    for (int r = 0; r < 4; ++r) {
      const int m = by * 128 + wm * 64 + (mo + m2) * 16 + lane_hi * 4 + r;
      const int e = m >> 9, i = m & 511;
      const size_t ci = (size_t)(e * 512 + i) * HID + h;
      u16 hv;
      if (t < lenv[m2][r]) {
        const float c_old = cold[m2][r];
        const float zi = accF[m2][0][r] + b2v[0] + pi * c_old;
        const float zj = accF[m2][1][r] + b2v[1];
        const float zf = accF[m2][2][r] + b2v[2] + pf * c_old;  // FORGET_BIAS folded in b2
        const float zo = accF[m2][3][r] + b2v[3];
        const float ig = fsig(zi), fg = fsig(zf);
        const float cn = fg * c_old + ig * ftanhf(zj);
        const float og = fsig(zo + po * cn);
        const float hn = og * ftanhf(cn);
        c_st[ci] = cn;
        hv = f2bf(hn);
      } else {
        hv = hprev[m2][r];
      }
      h_nxt[ci] = hv;
    }
  }
}

// ---------------- generic bf16 GEMM: C[m][n] = sum_k A[m][k] * Bn[n][k] ----------------
template <int OUT_BF16>
__global__ __launch_bounds__(256) void k_gemm(
    const u16* __restrict__ A, const u16* __restrict__ Bn,
    void* __restrict__ Cout, int K, int ldc)
{
  __shared__ u16 lA[128 * 64];
  __shared__ u16 lB[128 * 64];
  const int tid = threadIdx.x;
  const int lane = tid & 63, wid = tid >> 6;
  const int wm = wid >> 1, wn = wid & 1;
  const int lane_lo = lane & 15, lane_hi = lane >> 4;
  const int bx = blockIdx.x, by = blockIdx.y;

  f32x4 acc[4][4];
  const f32x4 zz = {0.f, 0.f, 0.f, 0.f};
#pragma unroll
  for (int a = 0; a < 4; ++a)
#pragma unroll
    for (int bb = 0; bb < 4; ++bb) acc[a][bb] = zz;

  const int nkt = K >> 6;
  for (int kt = 0; kt < nkt; ++kt) {
    const int kb = kt * 64;
#pragma unroll
    for (int j = 0; j < 4; ++j) {
      const int cbase = (j * 4 + wid) * 64;
      const int ch = cbase + lane;
      const int r = ch >> 3;
      const int srcoff = ((((ch & 7) << 4) ^ ((r & 7) << 4)) >> 1);
      ld_lds16(A + (size_t)(by * 128 + r) * K + kb + srcoff, &lA[cbase * 8]);
    }
#pragma unroll
    for (int j = 0; j < 4; ++j) {
      const int cbase = (j * 4 + wid) * 64;
      const int ch = cbase + lane;
      const int r = ch >> 3;
      const int srcoff = ((((ch & 7) << 4) ^ ((r & 7) << 4)) >> 1);
      ld_lds16(Bn + (size_t)(bx * 128 + r) * K + kb + srcoff, &lB[cbase * 8]);
    }
    __syncthreads();
#pragma unroll
    for (int kk = 0; kk < 2; ++kk) {
      bf16x8 aF[4], bF[4];
#pragma unroll
      for (int mi = 0; mi < 4; ++mi) {
        const int rr = wm * 64 + mi * 16 + lane_lo;
        const int byo = rr * 128 + ((kk * 64 + lane_hi * 16) ^ ((rr & 7) << 4));
        aF[mi] = *(const bf16x8*)((const char*)lA + byo);
      }
#pragma unroll
      for (int ni = 0; ni < 4; ++ni) {
        const int rr = wn * 64 + ni * 16 + lane_lo;
        const int byo = rr * 128 + ((kk * 64 + lane_hi * 16) ^ ((rr & 7) << 4));
        bF[ni] = *(const bf16x8*)((const char*)lB + byo);
      }
#pragma unroll
      for (int mi = 0; mi < 4; ++mi)
#pragma unroll
        for (int ni = 0; ni < 4; ++ni)
          acc[mi][ni] = __builtin_amdgcn_mfma_f32_16x16x32_bf16(aF[mi], bF[ni], acc[mi][ni], 0, 0, 0);
    }
    __syncthreads();
  }

#pragma unroll
  for (int mi = 0; mi < 4; ++mi)
#pragma unroll
    for (int r = 0; r < 4; ++r) {
      const int m = by * 128 + wm * 64 + mi * 16 + lane_hi * 4 + r;
#pragma unroll
      for (int ni = 0; ni < 4; ++ni) {
        const int col = bx * 128 + wn * 64 + ni * 16 + lane_lo;
        const float v = acc[mi][ni][r];
        if (OUT_BF16) ((u16*)Cout)[(size_t)m * ldc + col] = f2bf(v);
        else ((float*)Cout)[(size_t)m * ldc + col] = v;
      }
    }
}

// ---------------- prep kernels ----------------
// Fragment-major W pack (verified in R13):
// Wfm[((((bx*2+wn)*2+kw)*24+kt)*4+ni)*512 + lane*8 + e] = bf16(W[k][n])
__global__ void k_pack(const float* __restrict__ W, u16* __restrict__ Wfm) {
  __shared__ float tile[64][65];
  const int n0 = blockIdx.x * 64;
  const int k0 = blockIdx.y * 64;
  const int tid = threadIdx.x;
  const int c = tid & 63, rq = tid >> 6;
  for (int rr = 0; rr < 64; rr += 4)
    tile[rr + rq][c] = W[(size_t)(k0 + rr + rq) * 4096 + n0 + c];
  __syncthreads();
  const int gate = n0 >> 10;
  const int h0 = n0 & 1023;
  const int kt = k0 >> 6;
  for (int cc = tid; cc < 512; cc += 256) {
    const int hh = cc >> 3;
    const int k8 = cc & 7;
    const int h = h0 + hh;
    const int np = ((h >> 4) << 6) + (gate << 4) + (h & 15);
    const int bx = np >> 7, wn = (np >> 6) & 1, ni = (np >> 4) & 3, llo = np & 15;
    const int kw = k8 >> 2, lhi = k8 & 3;
    const int lane = lhi * 16 + llo;
    u16 oc[8];
#pragma unroll
    for (int e = 0; e < 8; ++e)
      oc[e] = f2bf(tile[k8 * 8 + e][hh]);
    const size_t o = ((((size_t)(bx * 2 + wn) * 2 + kw) * 24 + kt) * 4 + ni) * 512 + lane * 8;
    *(ushort4*)(Wfm + o)     = *(ushort4*)&oc[0];
    *(ushort4*)(Wfm + o + 4) = *(ushort4*)&oc[4];
  }
}

// out[n'][k] (bf16) = in[k][n] (f32); no perm (used for M^T)
__global__ void k_transpose(const float* __restrict__ in, u16* __restrict__ out,
                            int K_, int N_)
{
  __shared__ float tile[64][65];
  const int tid = threadIdx.x;
  const int k0 = blockIdx.y * 64, n0 = blockIdx.x * 64;
  const int c = tid & 63, rq = tid >> 6;
  for (int rr = 0; rr < 64; rr += 4)
    tile[rr + rq][c] = in[(size_t)(k0 + rr + rq) * N_ + n0 + c];
  __syncthreads();
  for (int nr0 = 0; nr0 < 64; nr0 += 4) {
    const int nr = nr0 + rq;
    out[(size_t)(n0 + nr) * K_ + k0 + c] = f2bf(tile[c][nr]);
  }
}

__global__ void k_bias(const float* __restrict__ b, float* __restrict__ b2) {
  const int n = blockIdx.x * 256 + threadIdx.x;
  if (n < 4096) {
    const int g = n >> 10, hh = n & 1023;
    const int np = ((hh >> 4) << 6) + (g << 4) + (hh & 15);
    b2[np] = b[n] + (g == 2 ? 2.0f : 0.0f);
  }
}

__global__ void k_cvt(const float4* __restrict__ in, u16* __restrict__ out, size_t n4) {
  size_t idx = (size_t)blockIdx.x * blockDim.x + threadIdx.x;
  const size_t stride = (size_t)gridDim.x * blockDim.x;
  for (; idx < n4; idx += stride) {
    const float4 v = in[idx];
    ushort4 o;
    o.x = f2bf(v.x); o.y = f2bf(v.y); o.z = f2bf(v.z); o.w = f2bf(v.w);
    *(ushort4*)(out + idx * 4) = o;
  }
}

__global__ void k_zero(uint4* __restrict__ p, size_t n) {
  size_t idx = (size_t)blockIdx.x * blockDim.x + threadIdx.x;
  const size_t stride = (size_t)gridDim.x * blockDim.x;
  const uint4 z = {0u, 0u, 0u, 0u};
  for (; idx < n; idx += stride) p[idx] = z;
}

// ---------------- loss ----------------
__global__ void k_loss1(const float* __restrict__ D, float* __restrict__ part) {
  __shared__ float sd[256];
  const int tid = threadIdx.x;
  float s = 0.f;
  for (int idx = blockIdx.x * 256 + tid; idx < 512 * 512; idx += 256 * 256) {
    const float x = D[idx];
    float sp;
    if (x > 20.f) sp = x;
    else if (x < -20.f) sp = __expf(x);
    else sp = __logf(1.0f + __expf(x));
    if ((idx >> 9) == (idx & 511)) sp -= x;
    s += sp;
  }
  sd[tid] = s;
  __syncthreads();
  for (int o = 128; o > 0; o >>= 1) { if (tid < o) sd[tid] += sd[tid + o]; __syncthreads(); }
  if (tid == 0) part[blockIdx.x] = sd[0];
}

__global__ void k_loss2(const float* __restrict__ part, float* __restrict__ out) {
  __shared__ float sd[256];
  const int tid = threadIdx.x;
  sd[tid] = part[tid];
  __syncthreads();
  for (int o = 128; o > 0; o >>= 1) { if (tid < o) sd[tid] += sd[tid + o]; __syncthreads(); }
  if (tid == 0) out[0] = sd[0] * (1.0f / (512.0f * 512.0f));
}

// ---------------- launch ----------------
extern "C" void kernel_launch(void* const* d_in, const int* in_sizes, int n_in,
                              void* d_out, int out_size, void* d_ws, size_t ws_size,
                              hipStream_t stream)
{
  const float* embF = (const float*)d_in[0];
  const float* W    = (const float*)d_in[1];
  const float* b    = (const float*)d_in[2];
  const float* p_i  = (const float*)d_in[3];
  const float* p_f  = (const float*)d_in[4];
  const float* p_o  = (const float*)d_in[5];
  const float* Mm   = (const float*)d_in[6];
  const int* tokQ   = (const int*)d_in[7];
  const int* tokR   = (const int*)d_in[8];
  const int* lenQ   = (const int*)d_in[9];
  const int* lenR   = (const int*)d_in[10];
  float* out = (float*)d_out;

  char* ws = (char*)d_ws;
  const size_t OFF_EMB  = 0;                       // 50000*512*2 = 51,200,000
  const size_t OFF_WFM  = 51200000;                // 4096*1536*2 = 12,582,912 (fragment-major)
  const size_t OFF_MT   = OFF_WFM + 12582912;      // 1024*1024*2 =  2,097,152
  const size_t OFF_B2   = OFF_MT + 2097152;        // 4096*4
  const size_t OFF_H    = OFF_B2 + 16384;          // 2buf*2enc*512*1024*2 = 4,194,304
  const size_t OFF_C    = OFF_H + 4194304;         // 2enc*512*1024*4 = 4,194,304
  const size_t OFF_QT   = OFF_C + 4194304;         // 512*1024*2 = 1,048,576
  const size_t OFF_PART = OFF_QT + 1048576;        // 256*4
  const size_t NEED = OFF_PART + 1024;
  if (ws_size < NEED) return;

  u16* embB  = (u16*)(ws + OFF_EMB);
  u16* Wfm   = (u16*)(ws + OFF_WFM);
  u16* MT    = (u16*)(ws + OFF_MT);
  float* b2  = (float*)(ws + OFF_B2);
  u16* hbuf  = (u16*)(ws + OFF_H);
  float* cst = (float*)(ws + OFF_C);
  u16* qt    = (u16*)(ws + OFF_QT);
  float* part= (float*)(ws + OFF_PART);

  // prep
  k_cvt<<<dim3(2048), dim3(256), 0, stream>>>((const float4*)embF, embB, (size_t)(50000 * 512 / 4));
  k_pack<<<dim3(64, 24), dim3(256), 0, stream>>>(W, Wfm);
  k_transpose<<<dim3(16, 16), dim3(256), 0, stream>>>(Mm, MT, 1024, 1024);
  k_bias<<<dim3(16), dim3(256), 0, stream>>>(b, b2);
  k_zero<<<dim3(256), dim3(256), 0, stream>>>((uint4*)hbuf, 131072);   // h buf0 (2 MB)
  k_zero<<<dim3(256), dim3(256), 0, stream>>>((uint4*)cst, 262144);    // c (4 MB)

  // recurrence: h double-buffered; t reads buf (t&1), writes buf ((t+1)&1); final state in buf 0
  const size_t HBUFSTRIDE = (size_t)2 * 512 * 1024;  // u16 elems per buffer
  for (int t = 0; t < 100; ++t) {
    u16* hc = hbuf + (size_t)(t & 1) * HBUFSTRIDE;
    u16* hn = hbuf + (size_t)((t + 1) & 1) * HBUFSTRIDE;
    k_step<<<dim3(256), dim3(512), 0, stream>>>(embB, Wfm, b2, p_i, p_f, p_o,
                                                tokQ, tokR, lenQ, lenR, hc, hn, cst, t);
  }

  // q_t = h_q @ M  (A = enc0 of buf0; B = M^T rows)
  k_gemm<1><<<dim3(8, 4), dim3(256), 0, stream>>>(hbuf, MT, qt, 1024, 1024);
  // distances = q_t @ h_r^T  (B rows = enc1 final h)
  k_gemm<0><<<dim3(4, 4), dim3(256), 0, stream>>>(qt, hbuf + (size_t)512 * 1024, out, 1024, 512);

  k_loss1<<<dim3(256), dim3(256), 0, stream>>>(out, part);
  k_loss2<<<dim3(1), dim3(256), 0, stream>>>(part, out + 262144);
}